// Round 2
// baseline (1891.693 us; speedup 1.0000x reference)
//
#include <hip/hip_runtime.h>

typedef __attribute__((ext_vector_type(8))) short short8;
typedef __attribute__((ext_vector_type(4))) float floatx4;

#define BM 128
#define BN 128
#define BK 32

__device__ inline short f2bf(float v) {
    unsigned u = __builtin_bit_cast(unsigned, v);
    unsigned r = (u + 0x7fffu + ((u >> 16) & 1u)) >> 16;
    return (short)r;
}
__device__ inline float bf2f(short s) {
    unsigned u = ((unsigned)(unsigned short)s) << 16;
    return __builtin_bit_cast(float, u);
}

// Expand 8 contiguous expanded-columns [c, c+8) of one row.
// Expanded layout: cols [0,F) = silu(x_f); cols [F,9F) = feature (c-F)>>3's 8 bases.
__device__ inline short8 expand8(const short* __restrict__ arow, int c, int F) {
    short8 outv;
    if (c < F) {
        short8 rv = *(const short8*)(arow + c);
#pragma unroll
        for (int q = 0; q < 8; ++q) {
            float v = bf2f(rv[q]);
            float sl = v / (1.f + __expf(-v));
            outv[q] = f2bf(sl);
        }
    } else {
        int f = (c - F) >> 3;
        float v = bf2f(arow[f]);
        // uniform cubic B-spline, knots -2.2 + 0.4*m, 8 kept bases
        float u = (v + 2.2f) * 2.5f;
        float fj = floorf(u);
        int jj = (int)fj;
        float t1 = u - fj;
        float ok = (jj >= 0 && jj <= 10) ? (1.f / 6.f) : 0.f;
        float t2 = t1 * t1, t3 = t2 * t1;
        float omt = 1.f - t1;
        short sw0 = f2bf(omt * omt * omt * ok);
        short sw1 = f2bf((3.f * t3 - 6.f * t2 + 4.f) * ok);
        short sw2 = f2bf((-3.f * t3 + 3.f * t2 + 3.f * t1 + 1.f) * ok);
        short sw3 = f2bf(t3 * ok);
#pragma unroll
        for (int s = 0; s < 8; ++s) {
            int rr = s - jj + 3;
            outv[s] = (rr == 0) ? sw0 : (rr == 1) ? sw1 : (rr == 2) ? sw2
                      : (rr == 3) ? sw3 : (short)0;
        }
    }
    return outv;
}

// ---------------------------------------------------------------------------
// Fused GEMM: C(M,N) bf16 = sum over <=2 segments of op(A_seg) @ W_seg^T
// mode 0: A used raw (bf16, K cols). mode 1: A raw has F cols; expanded
// on the fly to K=9F cols ([silu | bases]). Batched over blockIdx.z.
// ---------------------------------------------------------------------------
__global__ __launch_bounds__(256) void gemm_fused(
    const short* __restrict__ A0, int lda0, long sA0, int F0, int K0, int mode0,
    const short* __restrict__ W0, int ldw0, long sW0,
    const short* __restrict__ A1, int lda1, long sA1, int F1, int K1, int mode1,
    const short* __restrict__ W1, int ldw1, long sW1,
    short* __restrict__ C, int ldc, long sC)
{
    __shared__ short As[BM * BK];
    __shared__ short Ws[BN * BK];
    const int t = threadIdx.x;
    const int z = blockIdx.z;
    const int bm = blockIdx.x * BM;
    const int bn = blockIdx.y * BN;
    const int lane = t & 63, w = t >> 6;
    const int wm = (w >> 1) * 64, wn = (w & 1) * 64;
    const int lrow = lane & 15, quad = lane >> 4;

    floatx4 acc[4][4] = {};

    const short* A = A0 + (long)z * sA0;
    const short* W = W0 + (long)z * sW0;
    int K = K0, lda = lda0, ldw = ldw0, F = F0, mode = mode0;

    for (int seg = 0; seg < 2; ++seg) {
        for (int k0 = 0; k0 < K; k0 += BK) {
#pragma unroll
            for (int j = 0; j < 2; ++j) {
                int ci = j * 256 + t;
                int row = ci >> 2, cg = (ci & 3) * 8;
                if (mode == 0) {
                    const short* gp = A + (long)(bm + row) * lda + k0 + cg;
                    __builtin_amdgcn_global_load_lds(
                        (const __attribute__((address_space(1))) void*)gp,
                        (__attribute__((address_space(3))) void*)(As + ci * 8), 16, 0, 0);
                } else {
                    const short* arow = A + (long)(bm + row) * lda;
                    short8 ev = expand8(arow, k0 + cg, F);
                    *(short8*)(As + ci * 8) = ev;
                }
                const short* gq = W + (long)(bn + row) * ldw + k0 + cg;
                __builtin_amdgcn_global_load_lds(
                    (const __attribute__((address_space(1))) void*)gq,
                    (__attribute__((address_space(3))) void*)(Ws + ci * 8), 16, 0, 0);
            }
            __syncthreads();
            short8 af[4], bfr[4];
#pragma unroll
            for (int mi = 0; mi < 4; ++mi)
                af[mi] = *(const short8*)(As + (wm + mi * 16 + lrow) * BK + quad * 8);
#pragma unroll
            for (int ni = 0; ni < 4; ++ni)
                bfr[ni] = *(const short8*)(Ws + (wn + ni * 16 + lrow) * BK + quad * 8);
#pragma unroll
            for (int mi = 0; mi < 4; ++mi)
#pragma unroll
                for (int ni = 0; ni < 4; ++ni)
                    acc[mi][ni] = __builtin_amdgcn_mfma_f32_16x16x32_bf16(
                        af[mi], bfr[ni], acc[mi][ni], 0, 0, 0);
            __syncthreads();
        }
        A = A1 + (long)z * sA1; W = W1 + (long)z * sW1;
        K = K1; lda = lda1; ldw = ldw1; F = F1; mode = mode1;
    }

    short* Cz = C + (long)z * sC;
#pragma unroll
    for (int mi = 0; mi < 4; ++mi)
#pragma unroll
        for (int ni = 0; ni < 4; ++ni)
#pragma unroll
            for (int r = 0; r < 4; ++r) {
                int row = bm + wm + mi * 16 + quad * 4 + r;
                int col = bn + wn + ni * 16 + lrow;
                Cz[(long)row * ldc + col] = f2bf(acc[mi][ni][r]);
            }
}

// pack [base (rows, inF) | spline (rows, inF*8)] fp32 -> (rows, inF*9) bf16
__global__ __launch_bounds__(256) void pack_kan_kernel(const float* __restrict__ base,
                                                       const float* __restrict__ spl,
                                                       short* __restrict__ out, int inF)
{
    int c = blockIdx.x * 256 + threadIdx.x;
    long r = blockIdx.y;
    int K9 = inF * 9;
    float v = (c < inF) ? base[r * inF + c] : spl[r * (long)inF * 8 + (c - inF)];
    out[r * (long)K9 + c] = f2bf(v);
}

__global__ __launch_bounds__(256) void convert_kernel(const float* __restrict__ src,
                                                      short* __restrict__ dst, long n)
{
    long idx = blockIdx.x * 256L + threadIdx.x;
    if (idx < n) dst[idx] = f2bf(src[idx]);
}

// x_t -> xraw bf16 and Agate cols [0,256)
__global__ __launch_bounds__(256) void cast_x_kernel(const float* __restrict__ x,
                                                     short* __restrict__ xraw,
                                                     short* __restrict__ Agate)
{
    int b = blockIdx.x, c = threadIdx.x;
    short s = f2bf(x[b * 256 + c]);
    xraw[b * 256 + c] = s;
    Agate[(long)b * 768 + c] = s;
}

// h_prev -> Agate cols [256,768)
__global__ __launch_bounds__(256) void cast_h_kernel(const float* __restrict__ h,
                                                     short* __restrict__ dst)
{
    long idx = blockIdx.x * 256L + threadIdx.x;  // B*H
    long b = idx >> 9; int hh = (int)(idx & 511);
    dst[b * 768 + 256 + hh] = f2bf(h[idx]);
}

// LayerNorm rows of 512 from bf16 zpre: out = LN(zpre + hh_b) * g + b
__global__ __launch_bounds__(256) void ln_kernel(const short* __restrict__ zpre,
                                                 const float* __restrict__ hh_b,
                                                 const float* __restrict__ ln_g,
                                                 const float* __restrict__ ln_b,
                                                 float* __restrict__ out)
{
    int row = blockIdx.x;
    int l = row >> 12;  // B = 4096 rows per sublayer
    int t = threadIdx.x;
    const short* x = zpre + (long)row * 512;
    float v0 = bf2f(x[t]) + hh_b[l * 512 + t];
    float v1 = bf2f(x[t + 256]) + hh_b[l * 512 + t + 256];
    float s = v0 + v1, sq = v0 * v0 + v1 * v1;
#pragma unroll
    for (int off = 32; off; off >>= 1) {
        s += __shfl_down(s, off);
        sq += __shfl_down(sq, off);
    }
    __shared__ float ls[4], lq[4];
    int w = t >> 6, lane = t & 63;
    if (lane == 0) { ls[w] = s; lq[w] = sq; }
    __syncthreads();
    float S = ls[0] + ls[1] + ls[2] + ls[3];
    float Q = lq[0] + lq[1] + lq[2] + lq[3];
    float mu = S * (1.f / 512.f);
    float var = Q * (1.f / 512.f) - mu * mu;
    float rstd = rsqrtf(var + 1e-5f);
    float* o = out + (long)row * 512;
    o[t]       = (v0 - mu) * rstd * ln_g[l * 512 + t]       + ln_b[l * 512 + t];
    o[t + 256] = (v1 - mu) * rstd * ln_g[l * 512 + t + 256] + ln_b[l * 512 + t + 256];
}

// final LSTM-style cell epilogue -> h_t, c_t
__global__ __launch_bounds__(256) void cell_epilogue(const short* __restrict__ gates,
                                                     const short* __restrict__ opre,
                                                     const float* __restrict__ c_prev,
                                                     const float* __restrict__ f_b,
                                                     const float* __restrict__ i_b,
                                                     const float* __restrict__ g_b,
                                                     const float* __restrict__ o_b,
                                                     float* __restrict__ out)
{
    long idx = blockIdx.x * 256L + threadIdx.x;  // B*H
    long b = idx >> 9; int h = (int)(idx & 511);
    const short* g = gates + b * 1536;
    float fp = bf2f(g[h]) + f_b[h];
    float ip = bf2f(g[512 + h]) + i_b[h];
    float gp = bf2f(g[1024 + h]) + g_b[h];
    float op = bf2f(opre[idx]) + o_b[h];
    float ft = 1.f / (1.f + __expf(-fp));
    float it = 1.f / (1.f + __expf(-ip));
    float gt = tanhf(gp);
    float ot = 1.f / (1.f + __expf(-op));
    float c = ft * c_prev[idx] + it * gt;
    out[idx] = ot * tanhf(c);
    out[idx + 2097152] = c;  // c_t at [BH, 2BH)
}

// ---------------------------------------------------------------------------
extern "C" void kernel_launch(void* const* d_in, const int* in_sizes, int n_in,
                              void* d_out, int out_size, void* d_ws, size_t ws_size,
                              hipStream_t stream)
{
    const float* x_t       = (const float*)d_in[0];
    const float* h_prev    = (const float*)d_in[1];
    const float* c_prev    = (const float*)d_in[2];
    const float* z_prev    = (const float*)d_in[3];
    const float* wx_base   = (const float*)d_in[4];
    const float* wx_spline = (const float*)d_in[5];
    const float* wh_base   = (const float*)d_in[6];
    const float* wh_spline = (const float*)d_in[7];
    const float* hz_base   = (const float*)d_in[8];
    const float* hz_spline = (const float*)d_in[9];
    const float* phi_base  = (const float*)d_in[10];
    const float* phi_spline= (const float*)d_in[11];
    const float* hh_w      = (const float*)d_in[12];
    const float* hh_b      = (const float*)d_in[13];
    const float* ln_g      = (const float*)d_in[14];
    const float* ln_b      = (const float*)d_in[15];
    const float* f_w       = (const float*)d_in[16];
    const float* f_b       = (const float*)d_in[17];
    const float* i_w       = (const float*)d_in[18];
    const float* i_b       = (const float*)d_in[19];
    const float* g_w       = (const float*)d_in[20];
    const float* g_b       = (const float*)d_in[21];
    const float* o_w       = (const float*)d_in[22];
    const float* o_b       = (const float*)d_in[23];
    float* out = (float*)d_out;

    const long BH = 4096L * 512;

    // ---- workspace carve (256B aligned); total ~114 MB ----
    char* p = (char*)d_ws;
    auto alloc = [&](size_t bytes) {
        char* q = p;
        p += (bytes + 255) & ~(size_t)255;
        return q;
    };
    short* Wx   = (short*)alloc(3L * 512 * 2304 * 2);
    short* Wh   = (short*)alloc(3L * 512 * 4608 * 2);
    short* Whz  = (short*)alloc(3L * 512 * 4608 * 2);
    short* Wphi = (short*)alloc(3L * 512 * 4608 * 2);
    short* HHb  = (short*)alloc(3L * 512 * 512 * 2);
    short* OWb  = (short*)alloc(512L * 1536 * 2);
    short* Wg   = (short*)alloc(1536L * 768 * 2);
    short* xraw = (short*)alloc(4096L * 256 * 2);
    short* Agate= (short*)alloc(4096L * 768 * 2);
    short* zraw = (short*)alloc(3L * 4096 * 512 * 2);
    short* sraw = (short*)alloc(3L * 4096 * 512 * 2);
    short* Rbuf = (short*)alloc(4096L * 1536 * 2);   // o in (B, L*512) layout
    short* zpre = (short*)alloc(3L * 4096 * 512 * 2);
    short* gbuf = sraw;   // (B,1536) — sraw dead after o-GEMM
    short* opre = zraw;   // (B,512)  — zraw dead after zpre-GEMM

    // ---- weight packing (fp32 -> bf16, [base|spline]) ----
    pack_kan_kernel<<<dim3(9, 1536), 256, 0, stream>>>(wx_base,  wx_spline,  Wx,   256);
    pack_kan_kernel<<<dim3(18, 1536), 256, 0, stream>>>(wh_base,  wh_spline,  Wh,   512);
    pack_kan_kernel<<<dim3(18, 1536), 256, 0, stream>>>(hz_base,  hz_spline,  Whz,  512);
    pack_kan_kernel<<<dim3(18, 1536), 256, 0, stream>>>(phi_base, phi_spline, Wphi, 512);
    convert_kernel<<<3072, 256, 0, stream>>>(hh_w, HHb, 786432);
    convert_kernel<<<3072, 256, 0, stream>>>(o_w, OWb, 786432);
    convert_kernel<<<1536, 256, 0, stream>>>(f_w, Wg,          393216);
    convert_kernel<<<1536, 256, 0, stream>>>(i_w, Wg + 393216, 393216);
    convert_kernel<<<1536, 256, 0, stream>>>(g_w, Wg + 786432, 393216);

    // ---- activation casts ----
    cast_x_kernel<<<4096, 256, 0, stream>>>(x_t, xraw, Agate);
    cast_h_kernel<<<8192, 256, 0, stream>>>(h_prev, Agate);
    convert_kernel<<<24576, 256, 0, stream>>>(z_prev, zraw, 6291456);

    // ---- s = kan(x, wx) + kan(z, wh)  (batched over L, fused expansion) ----
    gemm_fused<<<dim3(32, 4, 3), 256, 0, stream>>>(
        xraw, 256, 0,           256, 2304, 1, Wx, 2304, 512L * 2304,
        zraw, 512, 4096L * 512, 512, 4608, 1, Wh, 4608, 512L * 4608,
        sraw, 512, 4096L * 512);

    // ---- o = kan(s, phi) -> Rbuf in (B, L*512) layout ----
    gemm_fused<<<dim3(32, 4, 3), 256, 0, stream>>>(
        sraw, 512, 4096L * 512, 512, 4608, 1, Wphi, 4608, 512L * 4608,
        sraw, 512, 0,           512, 0,    0, Wphi, 4608, 0,
        Rbuf, 1536, 512);

    // ---- zpre = kan(o, hz) + z_prev @ hh_w^T ----
    gemm_fused<<<dim3(32, 4, 3), 256, 0, stream>>>(
        Rbuf, 1536, 512,        512, 4608, 1, Whz, 4608, 512L * 4608,
        zraw, 512, 4096L * 512, 512, 512,  0, HHb, 512,  512L * 512,
        zpre, 512, 4096L * 512);

    // ---- z_all = LN(zpre + hh_b) ----
    ln_kernel<<<12288, 256, 0, stream>>>(zpre, hh_b, ln_g, ln_b, out + 2 * BH);

    // ---- gates (f,i,g) pre-activations ----
    gemm_fused<<<dim3(32, 12, 1), 256, 0, stream>>>(
        Agate, 768, 0, 768, 768, 0, Wg, 768, 0,
        Agate, 768, 0, 768, 0,   0, Wg, 768, 0,
        gbuf, 1536, 0);

    // ---- output gate pre-activation ----
    gemm_fused<<<dim3(32, 4, 1), 256, 0, stream>>>(
        Rbuf, 1536, 0, 1536, 1536, 0, OWb, 1536, 0,
        Rbuf, 1536, 0, 1536, 0,    0, OWb, 1536, 0,
        opre, 512, 0);

    // ---- h_t, c_t ----
    cell_epilogue<<<8192, 256, 0, stream>>>(gbuf, opre, c_prev, f_b, i_b, g_b, o_b, out);
}

// Round 3
// 931.285 us; speedup vs baseline: 2.0313x; 2.0313x over previous
//
#include <hip/hip_runtime.h>

typedef __attribute__((ext_vector_type(8))) short short8;
typedef __attribute__((ext_vector_type(4))) float floatx4;

#define BM 128
#define BN 128
#define BK 32

__device__ inline short f2bf(float v) {
    unsigned u = __builtin_bit_cast(unsigned, v);
    unsigned r = (u + 0x7fffu + ((u >> 16) & 1u)) >> 16;
    return (short)r;
}
__device__ inline float bf2f(short s) {
    unsigned u = ((unsigned)(unsigned short)s) << 16;
    return __builtin_bit_cast(float, u);
}

// spline weights for value v: 8 kept bases, 4 nonzero starting at index j
__device__ inline void spline8(float v, short* arr) {
    float u = (v + 2.2f) * 2.5f;
    float fj = floorf(u);
    int jj = (int)fj;
    float t1 = u - fj;
    float ok = (jj >= 0 && jj <= 10) ? (1.f / 6.f) : 0.f;
    float t2 = t1 * t1, t3 = t2 * t1;
    float omt = 1.f - t1;
    short sw0 = f2bf(omt * omt * omt * ok);
    short sw1 = f2bf((3.f * t3 - 6.f * t2 + 4.f) * ok);
    short sw2 = f2bf((-3.f * t3 + 3.f * t2 + 3.f * t1 + 1.f) * ok);
    short sw3 = f2bf(t3 * ok);
#pragma unroll
    for (int s = 0; s < 8; ++s) {
        int rr = s - jj + 3;
        arr[s] = (rr == 0) ? sw0 : (rr == 1) ? sw1 : (rr == 2) ? sw2
                 : (rr == 3) ? sw3 : (short)0;
    }
}

// Expand 8 contiguous expanded-columns [c, c+8) of one row (bf16 source).
__device__ inline short8 expand8(const short* __restrict__ arow, int c, int F) {
    short8 outv;
    if (c < F) {
        short8 rv = *(const short8*)(arow + c);
#pragma unroll
        for (int q = 0; q < 8; ++q) {
            float v = bf2f(rv[q]);
            outv[q] = f2bf(v / (1.f + __expf(-v)));
        }
    } else {
        int f = (c - F) >> 3;
        float v = bf2f(arow[f]);
        short arr[8];
        spline8(v, arr);
        outv = *(const short8*)arr;
    }
    return outv;
}

// ---------------------------------------------------------------------------
// GEMM: C(M,N) bf16 = sum over <=2 segments of op(A_seg) @ W_seg^T
// mode 0: A raw bf16 (K cols, global_load_lds staging). mode 1: A raw has F
// cols, expanded on the fly to K=9F ([silu | bases]). Batched over blockIdx.z.
// ---------------------------------------------------------------------------
__global__ __launch_bounds__(256) void gemm_fused(
    const short* __restrict__ A0, int lda0, long sA0, int F0, int K0, int mode0,
    const short* __restrict__ W0, int ldw0, long sW0,
    const short* __restrict__ A1, int lda1, long sA1, int F1, int K1, int mode1,
    const short* __restrict__ W1, int ldw1, long sW1,
    short* __restrict__ C, int ldc, long sC)
{
    __shared__ short As[BM * BK];
    __shared__ short Ws[BN * BK];
    const int t = threadIdx.x;
    const int z = blockIdx.z;
    const int bm = blockIdx.x * BM;
    const int bn = blockIdx.y * BN;
    const int lane = t & 63, w = t >> 6;
    const int wm = (w >> 1) * 64, wn = (w & 1) * 64;
    const int lrow = lane & 15, quad = lane >> 4;

    floatx4 acc[4][4] = {};

    const short* A = A0 + (long)z * sA0;
    const short* W = W0 + (long)z * sW0;
    int K = K0, lda = lda0, ldw = ldw0, F = F0, mode = mode0;

    for (int seg = 0; seg < 2; ++seg) {
        for (int k0 = 0; k0 < K; k0 += BK) {
#pragma unroll
            for (int j = 0; j < 2; ++j) {
                int ci = j * 256 + t;
                int row = ci >> 2, cg = (ci & 3) * 8;
                if (mode == 0) {
                    const short* gp = A + (long)(bm + row) * lda + k0 + cg;
                    __builtin_amdgcn_global_load_lds(
                        (const __attribute__((address_space(1))) void*)gp,
                        (__attribute__((address_space(3))) void*)(As + ci * 8), 16, 0, 0);
                } else {
                    const short* arow = A + (long)(bm + row) * lda;
                    short8 ev = expand8(arow, k0 + cg, F);
                    *(short8*)(As + ci * 8) = ev;
                }
                const short* gq = W + (long)(bn + row) * ldw + k0 + cg;
                __builtin_amdgcn_global_load_lds(
                    (const __attribute__((address_space(1))) void*)gq,
                    (__attribute__((address_space(3))) void*)(Ws + ci * 8), 16, 0, 0);
            }
            __syncthreads();
            short8 af[4], bfr[4];
#pragma unroll
            for (int mi = 0; mi < 4; ++mi)
                af[mi] = *(const short8*)(As + (wm + mi * 16 + lrow) * BK + quad * 8);
#pragma unroll
            for (int ni = 0; ni < 4; ++ni)
                bfr[ni] = *(const short8*)(Ws + (wn + ni * 16 + lrow) * BK + quad * 8);
#pragma unroll
            for (int mi = 0; mi < 4; ++mi)
#pragma unroll
                for (int ni = 0; ni < 4; ++ni)
                    acc[mi][ni] = __builtin_amdgcn_mfma_f32_16x16x32_bf16(
                        af[mi], bfr[ni], acc[mi][ni], 0, 0, 0);
            __syncthreads();
        }
        A = A1 + (long)z * sA1; W = W1 + (long)z * sW1;
        K = K1; lda = lda1; ldw = ldw1; F = F1; mode = mode1;
    }

    short* Cz = C + (long)z * sC;
#pragma unroll
    for (int mi = 0; mi < 4; ++mi)
#pragma unroll
        for (int ni = 0; ni < 4; ++ni)
#pragma unroll
            for (int r = 0; r < 4; ++r) {
                int row = bm + wm + mi * 16 + quad * 4 + r;
                int col = bn + wn + ni * 16 + lrow;
                Cz[(long)row * ldc + col] = f2bf(acc[mi][ni][r]);
            }
}

// ---------------------------------------------------------------------------
// Expand fp32 x (rows, inF) -> out (rows, inF*9) bf16 = [silu | 8 bases];
// optional raw bf16 copy. grid: (inF/256, rows)
// ---------------------------------------------------------------------------
__global__ __launch_bounds__(256) void expand_f32_kernel(
    const float* __restrict__ x, int inF,
    short* __restrict__ out,
    short* __restrict__ raw, long raw_row_stride, long raw_l_stride, int rows_per_l)
{
    int i = blockIdx.x * 256 + threadIdx.x;
    int r = blockIdx.y;
    float v = x[(long)r * inF + i];

    long ob = (long)r * inF * 9;
    out[ob + i] = f2bf(v / (1.f + __expf(-v)));

    short arr[8];
    spline8(v, arr);
    *(short8*)(out + ob + inF + (long)i * 8) = *(const short8*)arr;

    if (raw) {
        int l = r / rows_per_l;
        int rb = r - l * rows_per_l;
        raw[(long)l * raw_l_stride + (long)rb * raw_row_stride + i] = f2bf(v);
    }
}

// Expand bf16 x (rows, inF) -> out (rows, inF*9) bf16. grid: (inF/256, rows)
__global__ __launch_bounds__(256) void expand_bf16_kernel(
    const short* __restrict__ x, int inF, short* __restrict__ out)
{
    int i = blockIdx.x * 256 + threadIdx.x;
    int r = blockIdx.y;
    float v = bf2f(x[(long)r * inF + i]);

    long ob = (long)r * inF * 9;
    out[ob + i] = f2bf(v / (1.f + __expf(-v)));

    short arr[8];
    spline8(v, arr);
    *(short8*)(out + ob + inF + (long)i * 8) = *(const short8*)arr;
}

// pack [base (rows, inF) | spline (rows, inF*8)] fp32 -> (rows, inF*9) bf16
__global__ __launch_bounds__(256) void pack_kan_kernel(const float* __restrict__ base,
                                                       const float* __restrict__ spl,
                                                       short* __restrict__ out, int inF)
{
    int c = blockIdx.x * 256 + threadIdx.x;
    long r = blockIdx.y;
    int K9 = inF * 9;
    float v = (c < inF) ? base[r * inF + c] : spl[r * (long)inF * 8 + (c - inF)];
    out[r * (long)K9 + c] = f2bf(v);
}

__global__ __launch_bounds__(256) void convert_kernel(const float* __restrict__ src,
                                                      short* __restrict__ dst, long n)
{
    long idx = blockIdx.x * 256L + threadIdx.x;
    if (idx < n) dst[idx] = f2bf(src[idx]);
}

// x_t -> xraw bf16 and Agate cols [0,256)
__global__ __launch_bounds__(256) void cast_x_kernel(const float* __restrict__ x,
                                                     short* __restrict__ xraw,
                                                     short* __restrict__ Agate)
{
    int b = blockIdx.x, c = threadIdx.x;
    short s = f2bf(x[b * 256 + c]);
    xraw[b * 256 + c] = s;
    Agate[(long)b * 768 + c] = s;
}

// h_prev -> Agate cols [256,768)
__global__ __launch_bounds__(256) void cast_h_kernel(const float* __restrict__ h,
                                                     short* __restrict__ dst)
{
    long idx = blockIdx.x * 256L + threadIdx.x;  // B*H
    long b = idx >> 9; int hh = (int)(idx & 511);
    dst[b * 768 + 256 + hh] = f2bf(h[idx]);
}

// LayerNorm rows of 512 from bf16 zpre: out = LN(zpre + hh_b) * g + b
__global__ __launch_bounds__(256) void ln_kernel(const short* __restrict__ zpre,
                                                 const float* __restrict__ hh_b,
                                                 const float* __restrict__ ln_g,
                                                 const float* __restrict__ ln_b,
                                                 float* __restrict__ out)
{
    int row = blockIdx.x;
    int l = row >> 12;  // 4096 rows per sublayer
    int t = threadIdx.x;
    const short* x = zpre + (long)row * 512;
    float v0 = bf2f(x[t]) + hh_b[l * 512 + t];
    float v1 = bf2f(x[t + 256]) + hh_b[l * 512 + t + 256];
    float s = v0 + v1, sq = v0 * v0 + v1 * v1;
#pragma unroll
    for (int off = 32; off; off >>= 1) {
        s += __shfl_down(s, off);
        sq += __shfl_down(sq, off);
    }
    __shared__ float ls[4], lq[4];
    int w = t >> 6, lane = t & 63;
    if (lane == 0) { ls[w] = s; lq[w] = sq; }
    __syncthreads();
    float S = ls[0] + ls[1] + ls[2] + ls[3];
    float Q = lq[0] + lq[1] + lq[2] + lq[3];
    float mu = S * (1.f / 512.f);
    float var = Q * (1.f / 512.f) - mu * mu;
    float rstd = rsqrtf(var + 1e-5f);
    float* o = out + (long)row * 512;
    o[t]       = (v0 - mu) * rstd * ln_g[l * 512 + t]       + ln_b[l * 512 + t];
    o[t + 256] = (v1 - mu) * rstd * ln_g[l * 512 + t + 256] + ln_b[l * 512 + t + 256];
}

// final LSTM-style cell epilogue -> h_t, c_t
__global__ __launch_bounds__(256) void cell_epilogue(const short* __restrict__ gates,
                                                     const short* __restrict__ opre,
                                                     const float* __restrict__ c_prev,
                                                     const float* __restrict__ f_b,
                                                     const float* __restrict__ i_b,
                                                     const float* __restrict__ g_b,
                                                     const float* __restrict__ o_b,
                                                     float* __restrict__ out)
{
    long idx = blockIdx.x * 256L + threadIdx.x;  // B*H
    long b = idx >> 9; int h = (int)(idx & 511);
    const short* g = gates + b * 1536;
    float fp = bf2f(g[h]) + f_b[h];
    float ip = bf2f(g[512 + h]) + i_b[h];
    float gp = bf2f(g[1024 + h]) + g_b[h];
    float op = bf2f(opre[idx]) + o_b[h];
    float ft = 1.f / (1.f + __expf(-fp));
    float it = 1.f / (1.f + __expf(-ip));
    float gt = tanhf(gp);
    float ot = 1.f / (1.f + __expf(-op));
    float c = ft * c_prev[idx] + it * gt;
    out[idx] = ot * tanhf(c);
    out[idx + 2097152] = c;
}

// ---------------------------------------------------------------------------
extern "C" void kernel_launch(void* const* d_in, const int* in_sizes, int n_in,
                              void* d_out, int out_size, void* d_ws, size_t ws_size,
                              hipStream_t stream)
{
    const float* x_t       = (const float*)d_in[0];
    const float* h_prev    = (const float*)d_in[1];
    const float* c_prev    = (const float*)d_in[2];
    const float* z_prev    = (const float*)d_in[3];
    const float* wx_base   = (const float*)d_in[4];
    const float* wx_spline = (const float*)d_in[5];
    const float* wh_base   = (const float*)d_in[6];
    const float* wh_spline = (const float*)d_in[7];
    const float* hz_base   = (const float*)d_in[8];
    const float* hz_spline = (const float*)d_in[9];
    const float* phi_base  = (const float*)d_in[10];
    const float* phi_spline= (const float*)d_in[11];
    const float* hh_w      = (const float*)d_in[12];
    const float* hh_b      = (const float*)d_in[13];
    const float* ln_g      = (const float*)d_in[14];
    const float* ln_b      = (const float*)d_in[15];
    const float* f_w       = (const float*)d_in[16];
    const float* f_b       = (const float*)d_in[17];
    const float* i_w       = (const float*)d_in[18];
    const float* i_b       = (const float*)d_in[19];
    const float* g_w       = (const float*)d_in[20];
    const float* g_b       = (const float*)d_in[21];
    const float* o_w       = (const float*)d_in[22];
    const float* o_b       = (const float*)d_in[23];
    float* out = (float*)d_out;
    const long BH = 4096L * 512;

    char* p = (char*)d_ws;
    auto alloc = [&](size_t bytes) {
        char* q = p;
        p += (bytes + 255) & ~(size_t)255;
        return q;
    };

    // shared weight packs (both paths)
    short* Wx   = (short*)alloc(3L * 512 * 2304 * 2);
    short* Wh   = (short*)alloc(3L * 512 * 4608 * 2);
    short* Whz  = (short*)alloc(3L * 512 * 4608 * 2);
    short* Wphi = (short*)alloc(3L * 512 * 4608 * 2);
    short* HHb  = (short*)alloc(3L * 512 * 512 * 2);
    short* OWb  = (short*)alloc(512L * 1536 * 2);
    short* Wg   = (short*)alloc(1536L * 768 * 2);
    short* Agate= (short*)alloc(4096L * 768 * 2);
    short* zraw = (short*)alloc(3L * 4096 * 512 * 2);
    short* sraw = (short*)alloc(3L * 4096 * 512 * 2);   // later aliased as zpre (fast path)

    pack_kan_kernel<<<dim3(9, 1536), 256, 0, stream>>>(wx_base,  wx_spline,  Wx,   256);
    pack_kan_kernel<<<dim3(18, 1536), 256, 0, stream>>>(wh_base,  wh_spline,  Wh,   512);
    pack_kan_kernel<<<dim3(18, 1536), 256, 0, stream>>>(hz_base,  hz_spline,  Whz,  512);
    pack_kan_kernel<<<dim3(18, 1536), 256, 0, stream>>>(phi_base, phi_spline, Wphi, 512);
    convert_kernel<<<3072, 256, 0, stream>>>(hh_w, HHb, 786432);
    convert_kernel<<<3072, 256, 0, stream>>>(o_w, OWb, 786432);
    convert_kernel<<<1536, 256, 0, stream>>>(f_w, Wg,          393216);
    convert_kernel<<<1536, 256, 0, stream>>>(i_w, Wg + 393216, 393216);
    convert_kernel<<<1536, 256, 0, stream>>>(g_w, Wg + 786432, 393216);
    cast_h_kernel<<<8192, 256, 0, stream>>>(h_prev, Agate);

    if (ws_size >= (size_t)220000000) {
        // ============== FAST PATH: materialized expansion ==============
        short* XR   = (short*)alloc(4096L * 2304 * 2);     // Xe, later Rbuf
        short* Ebuf = (short*)alloc(3L * 4096 * 4608 * 2); // Ze -> Se -> Oe -> gbuf/opre
        short* Xe = XR;
        short* Rbuf = XR;
        short* zpre = sraw;
        short* gbuf = Ebuf;
        short* opre = Ebuf + 4096L * 1536;

        // expand x -> Xe (+ Agate raw), z_prev -> Ze (+ zraw)
        expand_f32_kernel<<<dim3(1, 4096), 256, 0, stream>>>(x_t, 256, Xe, Agate, 768, 0, 4096);
        expand_f32_kernel<<<dim3(2, 12288), 256, 0, stream>>>(z_prev, 512, Ebuf, zraw, 512, 4096L * 512, 4096);

        // s = Xe @ Wx^T + Ze @ Wh^T
        gemm_fused<<<dim3(32, 4, 3), 256, 0, stream>>>(
            Xe, 2304, 0, 0, 2304, 0,              Wx, 2304, 512L * 2304,
            Ebuf, 4608, 4096L * 4608, 0, 4608, 0, Wh, 4608, 512L * 4608,
            sraw, 512, 4096L * 512);

        // Se = expand(s)
        expand_bf16_kernel<<<dim3(2, 12288), 256, 0, stream>>>(sraw, 512, Ebuf);

        // o = Se @ Wphi^T -> Rbuf (B, L*512)
        gemm_fused<<<dim3(32, 4, 3), 256, 0, stream>>>(
            Ebuf, 4608, 4096L * 4608, 0, 4608, 0, Wphi, 4608, 512L * 4608,
            Ebuf, 4608, 0, 0, 0, 0,               Wphi, 4608, 0,
            Rbuf, 1536, 512);

        // Oe = expand(o) viewing Rbuf as (12288, 512), row j = b*3+l
        expand_bf16_kernel<<<dim3(2, 12288), 256, 0, stream>>>(Rbuf, 512, Ebuf);

        // zpre = Oe @ Whz^T + zraw @ hh_w^T   (Oe row for (b,l): Ebuf + l*4608 + b*13824)
        gemm_fused<<<dim3(32, 4, 3), 256, 0, stream>>>(
            Ebuf, 13824, 4608, 0, 4608, 0,        Whz, 4608, 512L * 4608,
            zraw, 512, 4096L * 512, 0, 512, 0,    HHb, 512, 512L * 512,
            zpre, 512, 4096L * 512);

        ln_kernel<<<12288, 256, 0, stream>>>(zpre, hh_b, ln_g, ln_b, out + 2 * BH);

        // gates (f,i,g)
        gemm_fused<<<dim3(32, 12, 1), 256, 0, stream>>>(
            Agate, 768, 0, 0, 768, 0, Wg, 768, 0,
            Agate, 768, 0, 0, 0, 0,   Wg, 768, 0,
            gbuf, 1536, 0);

        // output gate pre-activation
        gemm_fused<<<dim3(32, 4, 1), 256, 0, stream>>>(
            Rbuf, 1536, 0, 0, 1536, 0, OWb, 1536, 0,
            Rbuf, 1536, 0, 0, 0, 0,    OWb, 1536, 0,
            opre, 512, 0);

        cell_epilogue<<<8192, 256, 0, stream>>>(gbuf, opre, c_prev, f_b, i_b, g_b, o_b, out);
    } else {
        // ============== FALLBACK: round-1 fused-expansion path ==============
        short* xraw = (short*)alloc(4096L * 256 * 2);
        short* Rbuf = (short*)alloc(4096L * 1536 * 2);
        short* zpre = (short*)alloc(3L * 4096 * 512 * 2);
        short* gbuf = sraw;
        short* opre = zraw;

        cast_x_kernel<<<4096, 256, 0, stream>>>(x_t, xraw, Agate);
        convert_kernel<<<24576, 256, 0, stream>>>(z_prev, zraw, 6291456);

        gemm_fused<<<dim3(32, 4, 3), 256, 0, stream>>>(
            xraw, 256, 0, 256, 2304, 1,           Wx, 2304, 512L * 2304,
            zraw, 512, 4096L * 512, 512, 4608, 1, Wh, 4608, 512L * 4608,
            sraw, 512, 4096L * 512);

        gemm_fused<<<dim3(32, 4, 3), 256, 0, stream>>>(
            sraw, 512, 4096L * 512, 512, 4608, 1, Wphi, 4608, 512L * 4608,
            sraw, 512, 0, 512, 0, 0,              Wphi, 4608, 0,
            Rbuf, 1536, 512);

        gemm_fused<<<dim3(32, 4, 3), 256, 0, stream>>>(
            Rbuf, 1536, 512, 512, 4608, 1,        Whz, 4608, 512L * 4608,
            zraw, 512, 4096L * 512, 512, 512, 0,  HHb, 512, 512L * 512,
            zpre, 512, 4096L * 512);

        ln_kernel<<<12288, 256, 0, stream>>>(zpre, hh_b, ln_g, ln_b, out + 2 * BH);

        gemm_fused<<<dim3(32, 12, 1), 256, 0, stream>>>(
            Agate, 768, 0, 768, 768, 0, Wg, 768, 0,
            Agate, 768, 0, 768, 0, 0,   Wg, 768, 0,
            gbuf, 1536, 0);

        gemm_fused<<<dim3(32, 4, 1), 256, 0, stream>>>(
            Rbuf, 1536, 0, 1536, 1536, 0, OWb, 1536, 0,
            Rbuf, 1536, 0, 1536, 0, 0,    OWb, 1536, 0,
            opre, 512, 0);

        cell_epilogue<<<8192, 256, 0, stream>>>(gbuf, opre, c_prev, f_b, i_b, g_b, o_b, out);
    }
}

// Round 4
// 860.305 us; speedup vs baseline: 2.1989x; 1.0825x over previous
//
#include <hip/hip_runtime.h>

typedef __attribute__((ext_vector_type(8))) short short8;
typedef __attribute__((ext_vector_type(4))) float floatx4;

__device__ inline short f2bf(float v) {
    unsigned u = __builtin_bit_cast(unsigned, v);
    unsigned r = (u + 0x7fffu + ((u >> 16) & 1u)) >> 16;
    return (short)r;
}
__device__ inline float bf2f(short s) {
    unsigned u = ((unsigned)(unsigned short)s) << 16;
    return __builtin_bit_cast(float, u);
}

// spline weights for value v: 8 kept bases, 4 nonzero starting at index j
__device__ inline void spline8(float v, short* arr) {
    float u = (v + 2.2f) * 2.5f;
    float fj = floorf(u);
    int jj = (int)fj;
    float t1 = u - fj;
    float ok = (jj >= 0 && jj <= 10) ? (1.f / 6.f) : 0.f;
    float t2 = t1 * t1, t3 = t2 * t1;
    float omt = 1.f - t1;
    short sw0 = f2bf(omt * omt * omt * ok);
    short sw1 = f2bf((3.f * t3 - 6.f * t2 + 4.f) * ok);
    short sw2 = f2bf((-3.f * t3 + 3.f * t2 + 3.f * t1 + 1.f) * ok);
    short sw3 = f2bf(t3 * ok);
#pragma unroll
    for (int s = 0; s < 8; ++s) {
        int rr = s - jj + 3;
        arr[s] = (rr == 0) ? sw0 : (rr == 1) ? sw1 : (rr == 2) ? sw2
                 : (rr == 3) ? sw3 : (short)0;
    }
}

// Expand 8 contiguous expanded-columns [c, c+8) of one row (bf16 source).
__device__ inline short8 expand8(const short* __restrict__ arow, int c, int F) {
    short8 outv;
    if (c < F) {
        short8 rv = *(const short8*)(arow + c);
#pragma unroll
        for (int q = 0; q < 8; ++q) {
            float v = bf2f(rv[q]);
            outv[q] = f2bf(v / (1.f + __expf(-v)));
        }
    } else {
        int f = (c - F) >> 3;
        float v = bf2f(arow[f]);
        short arr[8];
        spline8(v, arr);
        outv = *(const short8*)arr;
    }
    return outv;
}

// ---------------------------------------------------------------------------
// gemm64: C(M,N) bf16 = sum of <=2 segments A_seg(M,K) @ W_seg(N,K)^T, bf16 in.
// Tile 64x128, BK=32, 4 waves (wave tile 32x64). Pure global_load_lds staging.
// grid: (M/64, N/128, batch)
// ---------------------------------------------------------------------------
__global__ __launch_bounds__(256) void gemm64(
    const short* __restrict__ A0, int lda0, long sA0, int K0,
    const short* __restrict__ W0, int ldw0, long sW0,
    const short* __restrict__ A1, int lda1, long sA1, int K1,
    const short* __restrict__ W1, int ldw1, long sW1,
    short* __restrict__ C, int ldc, long sC)
{
    __shared__ short As[64 * 32];
    __shared__ short Ws[128 * 32];
    const int t = threadIdx.x;
    const int z = blockIdx.z;
    const int bm = blockIdx.x * 64;
    const int bn = blockIdx.y * 128;
    const int lane = t & 63, w = t >> 6;
    const int wm = (w >> 1) * 32, wn = (w & 1) * 64;
    const int lrow = lane & 15, quad = lane >> 4;

    floatx4 acc[2][4] = {};

    const short* A = A0 + (long)z * sA0;
    const short* W = W0 + (long)z * sW0;
    int K = K0, lda = lda0, ldw = ldw0;

    for (int seg = 0; seg < 2; ++seg) {
        for (int k0 = 0; k0 < K; k0 += 32) {
            {   // A: 64x32 = 256 16B chunks, one per thread
                int row = t >> 2, cg = (t & 3) * 8;
                const short* gp = A + (long)(bm + row) * lda + k0 + cg;
                __builtin_amdgcn_global_load_lds(
                    (const __attribute__((address_space(1))) void*)gp,
                    (__attribute__((address_space(3))) void*)(As + t * 8), 16, 0, 0);
            }
#pragma unroll
            for (int j = 0; j < 2; ++j) {  // W: 128x32 = 512 chunks, two per thread
                int cj = j * 256 + t;
                int row = cj >> 2, cg = (cj & 3) * 8;
                const short* gq = W + (long)(bn + row) * ldw + k0 + cg;
                __builtin_amdgcn_global_load_lds(
                    (const __attribute__((address_space(1))) void*)gq,
                    (__attribute__((address_space(3))) void*)(Ws + cj * 8), 16, 0, 0);
            }
            __syncthreads();
            short8 af[2], bfr[4];
#pragma unroll
            for (int mi = 0; mi < 2; ++mi)
                af[mi] = *(const short8*)(As + (wm + mi * 16 + lrow) * 32 + quad * 8);
#pragma unroll
            for (int ni = 0; ni < 4; ++ni)
                bfr[ni] = *(const short8*)(Ws + (wn + ni * 16 + lrow) * 32 + quad * 8);
#pragma unroll
            for (int mi = 0; mi < 2; ++mi)
#pragma unroll
                for (int ni = 0; ni < 4; ++ni)
                    acc[mi][ni] = __builtin_amdgcn_mfma_f32_16x16x32_bf16(
                        af[mi], bfr[ni], acc[mi][ni], 0, 0, 0);
            __syncthreads();
        }
        A = A1 + (long)z * sA1; W = W1 + (long)z * sW1;
        K = K1; lda = lda1; ldw = ldw1;
    }

    short* Cz = C + (long)z * sC;
#pragma unroll
    for (int mi = 0; mi < 2; ++mi)
#pragma unroll
        for (int ni = 0; ni < 4; ++ni)
#pragma unroll
            for (int r = 0; r < 4; ++r) {
                int row = bm + wm + mi * 16 + quad * 4 + r;
                int col = bn + wn + ni * 16 + lrow;
                Cz[(long)row * ldc + col] = f2bf(acc[mi][ni][r]);
            }
}

// ---------------------------------------------------------------------------
// Fallback GEMM (round-1 structure): 128x128 tile, optional fused expansion.
// ---------------------------------------------------------------------------
__global__ __launch_bounds__(256) void gemm_fused(
    const short* __restrict__ A0, int lda0, long sA0, int F0, int K0, int mode0,
    const short* __restrict__ W0, int ldw0, long sW0,
    const short* __restrict__ A1, int lda1, long sA1, int F1, int K1, int mode1,
    const short* __restrict__ W1, int ldw1, long sW1,
    short* __restrict__ C, int ldc, long sC)
{
    __shared__ short As[128 * 32];
    __shared__ short Ws[128 * 32];
    const int t = threadIdx.x;
    const int z = blockIdx.z;
    const int bm = blockIdx.x * 128;
    const int bn = blockIdx.y * 128;
    const int lane = t & 63, w = t >> 6;
    const int wm = (w >> 1) * 64, wn = (w & 1) * 64;
    const int lrow = lane & 15, quad = lane >> 4;

    floatx4 acc[4][4] = {};

    const short* A = A0 + (long)z * sA0;
    const short* W = W0 + (long)z * sW0;
    int K = K0, lda = lda0, ldw = ldw0, F = F0, mode = mode0;

    for (int seg = 0; seg < 2; ++seg) {
        for (int k0 = 0; k0 < K; k0 += 32) {
#pragma unroll
            for (int j = 0; j < 2; ++j) {
                int ci = j * 256 + t;
                int row = ci >> 2, cg = (ci & 3) * 8;
                if (mode == 0) {
                    const short* gp = A + (long)(bm + row) * lda + k0 + cg;
                    __builtin_amdgcn_global_load_lds(
                        (const __attribute__((address_space(1))) void*)gp,
                        (__attribute__((address_space(3))) void*)(As + ci * 8), 16, 0, 0);
                } else {
                    const short* arow = A + (long)(bm + row) * lda;
                    short8 ev = expand8(arow, k0 + cg, F);
                    *(short8*)(As + ci * 8) = ev;
                }
                const short* gq = W + (long)(bn + row) * ldw + k0 + cg;
                __builtin_amdgcn_global_load_lds(
                    (const __attribute__((address_space(1))) void*)gq,
                    (__attribute__((address_space(3))) void*)(Ws + ci * 8), 16, 0, 0);
            }
            __syncthreads();
            short8 af[4], bfr[4];
#pragma unroll
            for (int mi = 0; mi < 4; ++mi)
                af[mi] = *(const short8*)(As + (wm + mi * 16 + lrow) * 32 + quad * 8);
#pragma unroll
            for (int ni = 0; ni < 4; ++ni)
                bfr[ni] = *(const short8*)(Ws + (wn + ni * 16 + lrow) * 32 + quad * 8);
#pragma unroll
            for (int mi = 0; mi < 4; ++mi)
#pragma unroll
                for (int ni = 0; ni < 4; ++ni)
                    acc[mi][ni] = __builtin_amdgcn_mfma_f32_16x16x32_bf16(
                        af[mi], bfr[ni], acc[mi][ni], 0, 0, 0);
            __syncthreads();
        }
        A = A1 + (long)z * sA1; W = W1 + (long)z * sW1;
        K = K1; lda = lda1; ldw = ldw1; F = F1; mode = mode1;
    }

    short* Cz = C + (long)z * sC;
#pragma unroll
    for (int mi = 0; mi < 4; ++mi)
#pragma unroll
        for (int ni = 0; ni < 4; ++ni)
#pragma unroll
            for (int r = 0; r < 4; ++r) {
                int row = bm + wm + mi * 16 + quad * 4 + r;
                int col = bn + wn + ni * 16 + lrow;
                Cz[(long)row * ldc + col] = f2bf(acc[mi][ni][r]);
            }
}

// ---------------------------------------------------------------------------
__global__ __launch_bounds__(256) void expand_f32_kernel(
    const float* __restrict__ x, int inF,
    short* __restrict__ out,
    short* __restrict__ raw, long raw_row_stride, long raw_l_stride, int rows_per_l)
{
    int i = blockIdx.x * 256 + threadIdx.x;
    int r = blockIdx.y;
    float v = x[(long)r * inF + i];

    long ob = (long)r * inF * 9;
    out[ob + i] = f2bf(v / (1.f + __expf(-v)));

    short arr[8];
    spline8(v, arr);
    *(short8*)(out + ob + inF + (long)i * 8) = *(const short8*)arr;

    if (raw) {
        int l = r / rows_per_l;
        int rb = r - l * rows_per_l;
        raw[(long)l * raw_l_stride + (long)rb * raw_row_stride + i] = f2bf(v);
    }
}

__global__ __launch_bounds__(256) void expand_bf16_kernel(
    const short* __restrict__ x, int inF, short* __restrict__ out)
{
    int i = blockIdx.x * 256 + threadIdx.x;
    int r = blockIdx.y;
    float v = bf2f(x[(long)r * inF + i]);

    long ob = (long)r * inF * 9;
    out[ob + i] = f2bf(v / (1.f + __expf(-v)));

    short arr[8];
    spline8(v, arr);
    *(short8*)(out + ob + inF + (long)i * 8) = *(const short8*)arr;
}

__global__ __launch_bounds__(256) void pack_kan_kernel(const float* __restrict__ base,
                                                       const float* __restrict__ spl,
                                                       short* __restrict__ out, int inF)
{
    int c = blockIdx.x * 256 + threadIdx.x;
    long r = blockIdx.y;
    int K9 = inF * 9;
    float v = (c < inF) ? base[r * inF + c] : spl[r * (long)inF * 8 + (c - inF)];
    out[r * (long)K9 + c] = f2bf(v);
}

__global__ __launch_bounds__(256) void convert_kernel(const float* __restrict__ src,
                                                      short* __restrict__ dst, long n)
{
    long idx = blockIdx.x * 256L + threadIdx.x;
    if (idx < n) dst[idx] = f2bf(src[idx]);
}

__global__ __launch_bounds__(256) void cast_x_kernel(const float* __restrict__ x,
                                                     short* __restrict__ xraw,
                                                     short* __restrict__ Agate)
{
    int b = blockIdx.x, c = threadIdx.x;
    short s = f2bf(x[b * 256 + c]);
    xraw[b * 256 + c] = s;
    Agate[(long)b * 768 + c] = s;
}

__global__ __launch_bounds__(256) void cast_h_kernel(const float* __restrict__ h,
                                                     short* __restrict__ dst)
{
    long idx = blockIdx.x * 256L + threadIdx.x;
    long b = idx >> 9; int hh = (int)(idx & 511);
    dst[b * 768 + 256 + hh] = f2bf(h[idx]);
}

__global__ __launch_bounds__(256) void ln_kernel(const short* __restrict__ zpre,
                                                 const float* __restrict__ hh_b,
                                                 const float* __restrict__ ln_g,
                                                 const float* __restrict__ ln_b,
                                                 float* __restrict__ out)
{
    int row = blockIdx.x;
    int l = row >> 12;
    int t = threadIdx.x;
    const short* x = zpre + (long)row * 512;
    float v0 = bf2f(x[t]) + hh_b[l * 512 + t];
    float v1 = bf2f(x[t + 256]) + hh_b[l * 512 + t + 256];
    float s = v0 + v1, sq = v0 * v0 + v1 * v1;
#pragma unroll
    for (int off = 32; off; off >>= 1) {
        s += __shfl_down(s, off);
        sq += __shfl_down(sq, off);
    }
    __shared__ float ls[4], lq[4];
    int w = t >> 6, lane = t & 63;
    if (lane == 0) { ls[w] = s; lq[w] = sq; }
    __syncthreads();
    float S = ls[0] + ls[1] + ls[2] + ls[3];
    float Q = lq[0] + lq[1] + lq[2] + lq[3];
    float mu = S * (1.f / 512.f);
    float var = Q * (1.f / 512.f) - mu * mu;
    float rstd = rsqrtf(var + 1e-5f);
    float* o = out + (long)row * 512;
    o[t]       = (v0 - mu) * rstd * ln_g[l * 512 + t]       + ln_b[l * 512 + t];
    o[t + 256] = (v1 - mu) * rstd * ln_g[l * 512 + t + 256] + ln_b[l * 512 + t + 256];
}

__global__ __launch_bounds__(256) void cell_epilogue(const short* __restrict__ gates,
                                                     const short* __restrict__ opre,
                                                     const float* __restrict__ c_prev,
                                                     const float* __restrict__ f_b,
                                                     const float* __restrict__ i_b,
                                                     const float* __restrict__ g_b,
                                                     const float* __restrict__ o_b,
                                                     float* __restrict__ out)
{
    long idx = blockIdx.x * 256L + threadIdx.x;
    long b = idx >> 9; int h = (int)(idx & 511);
    const short* g = gates + b * 1536;
    float fp = bf2f(g[h]) + f_b[h];
    float ip = bf2f(g[512 + h]) + i_b[h];
    float gp = bf2f(g[1024 + h]) + g_b[h];
    float op = bf2f(opre[idx]) + o_b[h];
    float ft = 1.f / (1.f + __expf(-fp));
    float it = 1.f / (1.f + __expf(-ip));
    float gt = tanhf(gp);
    float ot = 1.f / (1.f + __expf(-op));
    float c = ft * c_prev[idx] + it * gt;
    out[idx] = ot * tanhf(c);
    out[idx + 2097152] = c;
}

// ---------------------------------------------------------------------------
extern "C" void kernel_launch(void* const* d_in, const int* in_sizes, int n_in,
                              void* d_out, int out_size, void* d_ws, size_t ws_size,
                              hipStream_t stream)
{
    const float* x_t       = (const float*)d_in[0];
    const float* h_prev    = (const float*)d_in[1];
    const float* c_prev    = (const float*)d_in[2];
    const float* z_prev    = (const float*)d_in[3];
    const float* wx_base   = (const float*)d_in[4];
    const float* wx_spline = (const float*)d_in[5];
    const float* wh_base   = (const float*)d_in[6];
    const float* wh_spline = (const float*)d_in[7];
    const float* hz_base   = (const float*)d_in[8];
    const float* hz_spline = (const float*)d_in[9];
    const float* phi_base  = (const float*)d_in[10];
    const float* phi_spline= (const float*)d_in[11];
    const float* hh_w      = (const float*)d_in[12];
    const float* hh_b      = (const float*)d_in[13];
    const float* ln_g      = (const float*)d_in[14];
    const float* ln_b      = (const float*)d_in[15];
    const float* f_w       = (const float*)d_in[16];
    const float* f_b       = (const float*)d_in[17];
    const float* i_w       = (const float*)d_in[18];
    const float* i_b       = (const float*)d_in[19];
    const float* g_w       = (const float*)d_in[20];
    const float* g_b       = (const float*)d_in[21];
    const float* o_w       = (const float*)d_in[22];
    const float* o_b       = (const float*)d_in[23];
    float* out = (float*)d_out;
    const long BH = 4096L * 512;

    char* p = (char*)d_ws;
    auto alloc = [&](size_t bytes) {
        char* q = p;
        p += (bytes + 255) & ~(size_t)255;
        return q;
    };

    short* Wx   = (short*)alloc(3L * 512 * 2304 * 2);
    short* Wh   = (short*)alloc(3L * 512 * 4608 * 2);
    short* Whz  = (short*)alloc(3L * 512 * 4608 * 2);
    short* Wphi = (short*)alloc(3L * 512 * 4608 * 2);
    short* HHb  = (short*)alloc(3L * 512 * 512 * 2);
    short* OWb  = (short*)alloc(512L * 1536 * 2);
    short* Wg   = (short*)alloc(1536L * 768 * 2);
    short* Agate= (short*)alloc(4096L * 768 * 2);
    short* zraw = (short*)alloc(3L * 4096 * 512 * 2);
    short* sraw = (short*)alloc(3L * 4096 * 512 * 2);   // zpre alias on fast path

    pack_kan_kernel<<<dim3(9, 1536), 256, 0, stream>>>(wx_base,  wx_spline,  Wx,   256);
    pack_kan_kernel<<<dim3(18, 1536), 256, 0, stream>>>(wh_base,  wh_spline,  Wh,   512);
    pack_kan_kernel<<<dim3(18, 1536), 256, 0, stream>>>(hz_base,  hz_spline,  Whz,  512);
    pack_kan_kernel<<<dim3(18, 1536), 256, 0, stream>>>(phi_base, phi_spline, Wphi, 512);
    convert_kernel<<<3072, 256, 0, stream>>>(hh_w, HHb, 786432);
    convert_kernel<<<3072, 256, 0, stream>>>(o_w, OWb, 786432);
    convert_kernel<<<1536, 256, 0, stream>>>(f_w, Wg,          393216);
    convert_kernel<<<1536, 256, 0, stream>>>(i_w, Wg + 393216, 393216);
    convert_kernel<<<1536, 256, 0, stream>>>(g_w, Wg + 786432, 393216);
    cast_h_kernel<<<8192, 256, 0, stream>>>(h_prev, Agate);

    if (ws_size >= (size_t)210000000) {
        // ============== FAST PATH: materialized expansion, 64x128 GEMM tiles ==============
        short* XR   = (short*)alloc(4096L * 2304 * 2);     // Xe, later Rbuf
        short* Ebuf = (short*)alloc(3L * 4096 * 4608 * 2); // Ze -> Se -> Oe -> gbuf/opre
        short* Xe = XR;
        short* Rbuf = XR;
        short* zpre = sraw;
        short* gbuf = Ebuf;
        short* opre = Ebuf + 4096L * 1536;

        expand_f32_kernel<<<dim3(1, 4096), 256, 0, stream>>>(x_t, 256, Xe, Agate, 768, 0, 4096);
        expand_f32_kernel<<<dim3(2, 12288), 256, 0, stream>>>(z_prev, 512, Ebuf, zraw, 512, 4096L * 512, 4096);

        // s = Xe @ Wx^T + Ze @ Wh^T
        gemm64<<<dim3(64, 4, 3), 256, 0, stream>>>(
            Xe, 2304, 0, 2304,                 Wx, 2304, 512L * 2304,
            Ebuf, 4608, 4096L * 4608, 4608,    Wh, 4608, 512L * 4608,
            sraw, 512, 4096L * 512);

        expand_bf16_kernel<<<dim3(2, 12288), 256, 0, stream>>>(sraw, 512, Ebuf);

        // o = Se @ Wphi^T -> Rbuf (B, L*512)
        gemm64<<<dim3(64, 4, 3), 256, 0, stream>>>(
            Ebuf, 4608, 4096L * 4608, 4608,    Wphi, 4608, 512L * 4608,
            Ebuf, 4608, 0, 0,                  Wphi, 4608, 0,
            Rbuf, 1536, 512);

        expand_bf16_kernel<<<dim3(2, 12288), 256, 0, stream>>>(Rbuf, 512, Ebuf);

        // zpre = Oe @ Whz^T + zraw @ hh_w^T
        gemm64<<<dim3(64, 4, 3), 256, 0, stream>>>(
            Ebuf, 13824, 4608, 4608,           Whz, 4608, 512L * 4608,
            zraw, 512, 4096L * 512, 512,       HHb, 512, 512L * 512,
            zpre, 512, 4096L * 512);

        ln_kernel<<<12288, 256, 0, stream>>>(zpre, hh_b, ln_g, ln_b, out + 2 * BH);

        gemm64<<<dim3(64, 12, 1), 256, 0, stream>>>(
            Agate, 768, 0, 768,  Wg, 768, 0,
            Agate, 768, 0, 0,    Wg, 768, 0,
            gbuf, 1536, 0);

        gemm64<<<dim3(64, 4, 1), 256, 0, stream>>>(
            Rbuf, 1536, 0, 1536, OWb, 1536, 0,
            Rbuf, 1536, 0, 0,    OWb, 1536, 0,
            opre, 512, 0);

        cell_epilogue<<<8192, 256, 0, stream>>>(gbuf, opre, c_prev, f_b, i_b, g_b, o_b, out);
    } else {
        // ============== FALLBACK: round-1 fused-expansion path ==============
        short* xraw = (short*)alloc(4096L * 256 * 2);
        short* Rbuf = (short*)alloc(4096L * 1536 * 2);
        short* zpre = (short*)alloc(3L * 4096 * 512 * 2);
        short* gbuf = sraw;
        short* opre = zraw;

        cast_x_kernel<<<4096, 256, 0, stream>>>(x_t, xraw, Agate);
        convert_kernel<<<24576, 256, 0, stream>>>(z_prev, zraw, 6291456);

        gemm_fused<<<dim3(32, 4, 3), 256, 0, stream>>>(
            xraw, 256, 0, 256, 2304, 1,           Wx, 2304, 512L * 2304,
            zraw, 512, 4096L * 512, 512, 4608, 1, Wh, 4608, 512L * 4608,
            sraw, 512, 4096L * 512);

        gemm_fused<<<dim3(32, 4, 3), 256, 0, stream>>>(
            sraw, 512, 4096L * 512, 512, 4608, 1, Wphi, 4608, 512L * 4608,
            sraw, 512, 0, 512, 0, 0,              Wphi, 4608, 0,
            Rbuf, 1536, 512);

        gemm_fused<<<dim3(32, 4, 3), 256, 0, stream>>>(
            Rbuf, 1536, 512, 512, 4608, 1,        Whz, 4608, 512L * 4608,
            zraw, 512, 4096L * 512, 512, 512, 0,  HHb, 512, 512L * 512,
            zpre, 512, 4096L * 512);

        ln_kernel<<<12288, 256, 0, stream>>>(zpre, hh_b, ln_g, ln_b, out + 2 * BH);

        gemm_fused<<<dim3(32, 12, 1), 256, 0, stream>>>(
            Agate, 768, 0, 768, 768, 0, Wg, 768, 0,
            Agate, 768, 0, 768, 0, 0,   Wg, 768, 0,
            gbuf, 1536, 0);

        gemm_fused<<<dim3(32, 4, 1), 256, 0, stream>>>(
            Rbuf, 1536, 0, 1536, 1536, 0, OWb, 1536, 0,
            Rbuf, 1536, 0, 1536, 0, 0,    OWb, 1536, 0,
            opre, 512, 0);

        cell_epilogue<<<8192, 256, 0, stream>>>(gbuf, opre, c_prev, f_b, i_b, g_b, o_b, out);
    }
}

// Round 6
// 837.840 us; speedup vs baseline: 2.2578x; 1.0268x over previous
//
#include <hip/hip_runtime.h>

typedef __attribute__((ext_vector_type(8))) short short8;
typedef __attribute__((ext_vector_type(4))) float floatx4;

__device__ inline short f2bf(float v) {
    unsigned u = __builtin_bit_cast(unsigned, v);
    unsigned r = (u + 0x7fffu + ((u >> 16) & 1u)) >> 16;
    return (short)r;
}
__device__ inline float bf2f(short s) {
    unsigned u = ((unsigned)(unsigned short)s) << 16;
    return __builtin_bit_cast(float, u);
}

// spline weights for value v: 8 kept bases of the uniform cubic B-spline
__device__ inline void spline8(float v, short* arr) {
    float u = (v + 2.2f) * 2.5f;
    float fj = floorf(u);
    int jj = (int)fj;
    float t1 = u - fj;
    float ok = (jj >= 0 && jj <= 10) ? (1.f / 6.f) : 0.f;
    float t2 = t1 * t1, t3 = t2 * t1;
    float omt = 1.f - t1;
    short sw0 = f2bf(omt * omt * omt * ok);
    short sw1 = f2bf((3.f * t3 - 6.f * t2 + 4.f) * ok);
    short sw2 = f2bf((-3.f * t3 + 3.f * t2 + 3.f * t1 + 1.f) * ok);
    short sw3 = f2bf(t3 * ok);
#pragma unroll
    for (int s = 0; s < 8; ++s) {
        int rr = s - jj + 3;
        arr[s] = (rr == 0) ? sw0 : (rr == 1) ? sw1 : (rr == 2) ? sw2
                 : (rr == 3) ? sw3 : (short)0;
    }
}

// ---------------------------------------------------------------------------
// gemm64: C(M,N) bf16 = sum of <=2 segments A_seg(M,K) @ W_seg(N,K)^T, bf16 in.
// Tile 64x128, BK=32, 4 waves (wave tile 32x64). Pure global_load_lds staging.
// ROUND-4-PROVEN structure (replay-safe). swz=1: XCD-aware remap for grid
// (64,4,3) — each XCD (= linear_id%8) owns 8 M-slabs x 4 N x 3 z, with the
// 4 N-blocks of one (M,z) adjacent in time so the A-slab stays in that
// XCD's L2. Pure index permutation: no sync-semantics change.
// ---------------------------------------------------------------------------
__global__ __launch_bounds__(256) void gemm64(
    int swz,
    const short* __restrict__ A0, int lda0, long sA0, int K0,
    const short* __restrict__ W0, int ldw0, long sW0,
    const short* __restrict__ A1, int lda1, long sA1, int K1,
    const short* __restrict__ W1, int ldw1, long sW1,
    short* __restrict__ C, int ldc, long sC)
{
    __shared__ short As[64 * 32];
    __shared__ short Ws[128 * 32];
    const int t = threadIdx.x;
    int bxi = blockIdx.x, byi = blockIdx.y, bzi = blockIdx.z;
    if (swz) {                       // grid must be (64,4,3)
        int n = bxi + (byi << 6) + (bzi << 8);   // dispatch linear id, x fastest
        int k = n & 7, j = n >> 3;               // XCD k, per-XCD work index j in [0,96)
        byi = j & 3;                             // N-block fastest within XCD
        bxi = k * 8 + ((j >> 2) & 7);            // 8 M-slabs per XCD
        bzi = j >> 5;                            // sublayer
    }
    const int z = bzi;
    const int bm = bxi * 64;
    const int bn = byi * 128;
    const int lane = t & 63, w = t >> 6;
    const int wm = (w >> 1) * 32, wn = (w & 1) * 64;
    const int lrow = lane & 15, quad = lane >> 4;

    floatx4 acc[2][4] = {};

    const short* A = A0 + (long)z * sA0;
    const short* W = W0 + (long)z * sW0;
    int K = K0, lda = lda0, ldw = ldw0;

    for (int seg = 0; seg < 2; ++seg) {
        for (int k0 = 0; k0 < K; k0 += 32) {
            {   // A: 64x32 = 256 16B chunks, one per thread
                int row = t >> 2, cg = (t & 3) * 8;
                const short* gp = A + (long)(bm + row) * lda + k0 + cg;
                __builtin_amdgcn_global_load_lds(
                    (const __attribute__((address_space(1))) void*)gp,
                    (__attribute__((address_space(3))) void*)(As + t * 8), 16, 0, 0);
            }
#pragma unroll
            for (int j = 0; j < 2; ++j) {  // W: 128x32 = 512 chunks, two per thread
                int cj = j * 256 + t;
                int row = cj >> 2, cg = (cj & 3) * 8;
                const short* gq = W + (long)(bn + row) * ldw + k0 + cg;
                __builtin_amdgcn_global_load_lds(
                    (const __attribute__((address_space(1))) void*)gq,
                    (__attribute__((address_space(3))) void*)(Ws + cj * 8), 16, 0, 0);
            }
            __syncthreads();
            short8 af[2], bfr[4];
#pragma unroll
            for (int mi = 0; mi < 2; ++mi)
                af[mi] = *(const short8*)(As + (wm + mi * 16 + lrow) * 32 + quad * 8);
#pragma unroll
            for (int ni = 0; ni < 4; ++ni)
                bfr[ni] = *(const short8*)(Ws + (wn + ni * 16 + lrow) * 32 + quad * 8);
#pragma unroll
            for (int mi = 0; mi < 2; ++mi)
#pragma unroll
                for (int ni = 0; ni < 4; ++ni)
                    acc[mi][ni] = __builtin_amdgcn_mfma_f32_16x16x32_bf16(
                        af[mi], bfr[ni], acc[mi][ni], 0, 0, 0);
            __syncthreads();
        }
        A = A1 + (long)z * sA1; W = W1 + (long)z * sW1;
        K = K1; lda = lda1; ldw = ldw1;
    }

    short* Cz = C + (long)z * sC;
#pragma unroll
    for (int mi = 0; mi < 2; ++mi)
#pragma unroll
        for (int ni = 0; ni < 4; ++ni)
#pragma unroll
            for (int r = 0; r < 4; ++r) {
                int row = bm + wm + mi * 16 + quad * 4 + r;
                int col = bn + wn + ni * 16 + lrow;
                Cz[(long)row * ldc + col] = f2bf(acc[mi][ni][r]);
            }
}

// ---------------------------------------------------------------------------
// megapack: all weight fp32->bf16 packs in ONE launch. Hardcoded segment map.
// grid: 107520 blocks x 256
// ---------------------------------------------------------------------------
__global__ __launch_bounds__(256) void megapack(
    const float* __restrict__ wx_b, const float* __restrict__ wx_s,
    const float* __restrict__ wh_b, const float* __restrict__ wh_s,
    const float* __restrict__ hz_b, const float* __restrict__ hz_s,
    const float* __restrict__ phi_b, const float* __restrict__ phi_s,
    const float* __restrict__ hh_w, const float* __restrict__ o_w,
    const float* __restrict__ f_w, const float* __restrict__ i_w,
    const float* __restrict__ g_w,
    short* __restrict__ Wx, short* __restrict__ Wh, short* __restrict__ Whz,
    short* __restrict__ Wphi, short* __restrict__ HHb, short* __restrict__ OWb,
    short* __restrict__ Wg)
{
    int bid = blockIdx.x, tid = threadIdx.x;
    if (bid < 13824) {                       // Wx: (1536, 2304) kan-pack
        long idx = (long)bid * 256 + tid;
        int r = (int)(idx / 2304), c = (int)(idx % 2304);
        float v = (c < 256) ? wx_b[(long)r * 256 + c]
                            : wx_s[(long)r * 2048 + (c - 256)];
        Wx[idx] = f2bf(v);
    } else if (bid < 96768) {                // Wh/Whz/Wphi: (1536, 4608) each
        int jb = bid - 13824;
        int job = jb / 27648, lb = jb % 27648;
        const float* bp = (job == 0) ? wh_b : (job == 1) ? hz_b : phi_b;
        const float* sp = (job == 0) ? wh_s : (job == 1) ? hz_s : phi_s;
        short* dp = (job == 0) ? Wh : (job == 1) ? Whz : Wphi;
        long idx = (long)lb * 256 + tid;
        int r = (int)(idx / 4608), c = (int)(idx % 4608);
        float v = (c < 512) ? bp[(long)r * 512 + c]
                            : sp[(long)r * 4096 + (c - 512)];
        dp[idx] = f2bf(v);
    } else if (bid < 99840) {                // hh_w flat 786432
        long idx = (long)(bid - 96768) * 256 + tid;
        HHb[idx] = f2bf(hh_w[idx]);
    } else if (bid < 102912) {               // o_w flat 786432
        long idx = (long)(bid - 99840) * 256 + tid;
        OWb[idx] = f2bf(o_w[idx]);
    } else if (bid < 104448) {               // f_w flat 393216
        long idx = (long)(bid - 102912) * 256 + tid;
        Wg[idx] = f2bf(f_w[idx]);
    } else if (bid < 105984) {               // i_w
        long idx = (long)(bid - 104448) * 256 + tid;
        Wg[393216 + idx] = f2bf(i_w[idx]);
    } else {                                 // g_w
        long idx = (long)(bid - 105984) * 256 + tid;
        Wg[786432 + idx] = f2bf(g_w[idx]);
    }
}

// ---------------------------------------------------------------------------
// prep_acts: x expand -> Xe + Agate[:,0:256]; h cast -> Agate[:,256:768];
// z expand -> Ze + zraw.  grid: 36864 blocks x 256
// ---------------------------------------------------------------------------
__global__ __launch_bounds__(256) void prep_acts(
    const float* __restrict__ x_t, const float* __restrict__ h_prev,
    const float* __restrict__ z_prev,
    short* __restrict__ Xe, short* __restrict__ Agate,
    short* __restrict__ Ze, short* __restrict__ zraw)
{
    int bid = blockIdx.x, tid = threadIdx.x;
    if (bid < 4096) {                        // x: row bid, col tid
        int r = bid, i = tid;
        float v = x_t[(long)r * 256 + i];
        Agate[(long)r * 768 + i] = f2bf(v);
        long ob = (long)r * 2304;
        Xe[ob + i] = f2bf(v / (1.f + __expf(-v)));
        short arr[8];
        spline8(v, arr);
        *(short8*)(Xe + ob + 256 + (long)i * 8) = *(const short8*)arr;
    } else if (bid < 12288) {                // h cast
        long idx = (long)(bid - 4096) * 256 + tid;
        long b = idx >> 9; int hh = (int)(idx & 511);
        Agate[b * 768 + 256 + hh] = f2bf(h_prev[idx]);
    } else {                                 // z: 12288 rows x 512, 2 blocks/row
        int j = bid - 12288;
        int r = j >> 1, i = (j & 1) * 256 + tid;
        float v = z_prev[(long)r * 512 + i];
        zraw[(long)r * 512 + i] = f2bf(v);
        long ob = (long)r * 4608;
        Ze[ob + i] = f2bf(v / (1.f + __expf(-v)));
        short arr[8];
        spline8(v, arr);
        *(short8*)(Ze + ob + 512 + (long)i * 8) = *(const short8*)arr;
    }
}

// Expand bf16 x (rows, inF) -> out (rows, inF*9) bf16. grid: (inF/256, rows)
__global__ __launch_bounds__(256) void expand_bf16_kernel(
    const short* __restrict__ x, int inF, short* __restrict__ out)
{
    int i = blockIdx.x * 256 + threadIdx.x;
    int r = blockIdx.y;
    float v = bf2f(x[(long)r * inF + i]);

    long ob = (long)r * inF * 9;
    out[ob + i] = f2bf(v / (1.f + __expf(-v)));

    short arr[8];
    spline8(v, arr);
    *(short8*)(out + ob + inF + (long)i * 8) = *(const short8*)arr;
}

// LayerNorm rows of 512 from bf16 zpre: out = LN(zpre + hh_b) * g + b
__global__ __launch_bounds__(256) void ln_kernel(const short* __restrict__ zpre,
                                                 const float* __restrict__ hh_b,
                                                 const float* __restrict__ ln_g,
                                                 const float* __restrict__ ln_b,
                                                 float* __restrict__ out)
{
    int row = blockIdx.x;
    int l = row >> 12;
    int t = threadIdx.x;
    const short* x = zpre + (long)row * 512;
    float v0 = bf2f(x[t]) + hh_b[l * 512 + t];
    float v1 = bf2f(x[t + 256]) + hh_b[l * 512 + t + 256];
    float s = v0 + v1, sq = v0 * v0 + v1 * v1;
#pragma unroll
    for (int off = 32; off; off >>= 1) {
        s += __shfl_down(s, off);
        sq += __shfl_down(sq, off);
    }
    __shared__ float ls[4], lq[4];
    int w = t >> 6, lane = t & 63;
    if (lane == 0) { ls[w] = s; lq[w] = sq; }
    __syncthreads();
    float S = ls[0] + ls[1] + ls[2] + ls[3];
    float Q = lq[0] + lq[1] + lq[2] + lq[3];
    float mu = S * (1.f / 512.f);
    float var = Q * (1.f / 512.f) - mu * mu;
    float rstd = rsqrtf(var + 1e-5f);
    float* o = out + (long)row * 512;
    o[t]       = (v0 - mu) * rstd * ln_g[l * 512 + t]       + ln_b[l * 512 + t];
    o[t + 256] = (v1 - mu) * rstd * ln_g[l * 512 + t + 256] + ln_b[l * 512 + t + 256];
}

// final LSTM-style cell epilogue -> h_t, c_t
__global__ __launch_bounds__(256) void cell_epilogue(const short* __restrict__ gates,
                                                     const short* __restrict__ opre,
                                                     const float* __restrict__ c_prev,
                                                     const float* __restrict__ f_b,
                                                     const float* __restrict__ i_b,
                                                     const float* __restrict__ g_b,
                                                     const float* __restrict__ o_b,
                                                     float* __restrict__ out)
{
    long idx = blockIdx.x * 256L + threadIdx.x;
    long b = idx >> 9; int h = (int)(idx & 511);
    const short* g = gates + b * 1536;
    float fp = bf2f(g[h]) + f_b[h];
    float ip = bf2f(g[512 + h]) + i_b[h];
    float gp = bf2f(g[1024 + h]) + g_b[h];
    float op = bf2f(opre[idx]) + o_b[h];
    float ft = 1.f / (1.f + __expf(-fp));
    float it = 1.f / (1.f + __expf(-ip));
    float gt = tanhf(gp);
    float ot = 1.f / (1.f + __expf(-op));
    float c = ft * c_prev[idx] + it * gt;
    out[idx] = ot * tanhf(c);
    out[idx + 2097152] = c;
}

// ---------------------------------------------------------------------------
extern "C" void kernel_launch(void* const* d_in, const int* in_sizes, int n_in,
                              void* d_out, int out_size, void* d_ws, size_t ws_size,
                              hipStream_t stream)
{
    const float* x_t       = (const float*)d_in[0];
    const float* h_prev    = (const float*)d_in[1];
    const float* c_prev    = (const float*)d_in[2];
    const float* z_prev    = (const float*)d_in[3];
    const float* wx_base   = (const float*)d_in[4];
    const float* wx_spline = (const float*)d_in[5];
    const float* wh_base   = (const float*)d_in[6];
    const float* wh_spline = (const float*)d_in[7];
    const float* hz_base   = (const float*)d_in[8];
    const float* hz_spline = (const float*)d_in[9];
    const float* phi_base  = (const float*)d_in[10];
    const float* phi_spline= (const float*)d_in[11];
    const float* hh_w      = (const float*)d_in[12];
    const float* hh_b      = (const float*)d_in[13];
    const float* ln_g      = (const float*)d_in[14];
    const float* ln_b      = (const float*)d_in[15];
    const float* f_w       = (const float*)d_in[16];
    const float* f_b       = (const float*)d_in[17];
    const float* i_w       = (const float*)d_in[18];
    const float* i_b       = (const float*)d_in[19];
    const float* g_w       = (const float*)d_in[20];
    const float* g_b       = (const float*)d_in[21];
    const float* o_w       = (const float*)d_in[22];
    const float* o_b       = (const float*)d_in[23];
    float* out = (float*)d_out;
    const long BH = 4096L * 512;

    char* p = (char*)d_ws;
    auto alloc = [&](size_t bytes) {
        char* q = p;
        p += (bytes + 255) & ~(size_t)255;
        return q;
    };

    short* Wx   = (short*)alloc(3L * 512 * 2304 * 2);
    short* Wh   = (short*)alloc(3L * 512 * 4608 * 2);
    short* Whz  = (short*)alloc(3L * 512 * 4608 * 2);
    short* Wphi = (short*)alloc(3L * 512 * 4608 * 2);
    short* HHb  = (short*)alloc(3L * 512 * 512 * 2);
    short* OWb  = (short*)alloc(512L * 1536 * 2);
    short* Wg   = (short*)alloc(1536L * 768 * 2);
    short* Agate= (short*)alloc(4096L * 768 * 2);
    short* zraw = (short*)alloc(3L * 4096 * 512 * 2);
    short* sraw = (short*)alloc(3L * 4096 * 512 * 2);   // zpre alias later
    short* XR   = (short*)alloc(4096L * 2304 * 2);      // Xe, later Rbuf
    short* Ebuf = (short*)alloc(3L * 4096 * 4608 * 2);  // Ze -> Se -> Oe -> gbuf/opre
    short* Xe = XR;
    short* Rbuf = XR;
    short* zpre = sraw;
    short* gbuf = Ebuf;
    short* opre = Ebuf + 4096L * 1536;

    // ---- all weight packing in one launch ----
    megapack<<<107520, 256, 0, stream>>>(
        wx_base, wx_spline, wh_base, wh_spline, hz_base, hz_spline,
        phi_base, phi_spline, hh_w, o_w, f_w, i_w, g_w,
        Wx, Wh, Whz, Wphi, HHb, OWb, Wg);

    // ---- all activation prep in one launch ----
    prep_acts<<<36864, 256, 0, stream>>>(x_t, h_prev, z_prev, Xe, Agate, Ebuf, zraw);

    // ---- s = Xe @ Wx^T + Ze @ Wh^T ----
    gemm64<<<dim3(64, 4, 3), 256, 0, stream>>>(1,
        Xe, 2304, 0, 2304,                 Wx, 2304, 512L * 2304,
        Ebuf, 4608, 4096L * 4608, 4608,    Wh, 4608, 512L * 4608,
        sraw, 512, 4096L * 512);

    // ---- Se = expand(s) ----
    expand_bf16_kernel<<<dim3(2, 12288), 256, 0, stream>>>(sraw, 512, Ebuf);

    // ---- o = Se @ Wphi^T -> Rbuf (B, L*512) ----
    gemm64<<<dim3(64, 4, 3), 256, 0, stream>>>(1,
        Ebuf, 4608, 4096L * 4608, 4608,    Wphi, 4608, 512L * 4608,
        Ebuf, 4608, 0, 0,                  Wphi, 4608, 0,
        Rbuf, 1536, 512);

    // ---- Oe = expand(o), Rbuf viewed as (12288, 512) ----
    expand_bf16_kernel<<<dim3(2, 12288), 256, 0, stream>>>(Rbuf, 512, Ebuf);

    // ---- zpre = Oe @ Whz^T + zraw @ hh_w^T ----
    gemm64<<<dim3(64, 4, 3), 256, 0, stream>>>(1,
        Ebuf, 13824, 4608, 4608,           Whz, 4608, 512L * 4608,
        zraw, 512, 4096L * 512, 512,       HHb, 512, 512L * 512,
        zpre, 512, 4096L * 512);

    // ---- z_all = LN(zpre + hh_b) ----
    ln_kernel<<<12288, 256, 0, stream>>>(zpre, hh_b, ln_g, ln_b, out + 2 * BH);

    // ---- gates (f,i,g) pre-activations ----
    gemm64<<<dim3(64, 12, 1), 256, 0, stream>>>(0,
        Agate, 768, 0, 768,  Wg, 768, 0,
        Agate, 768, 0, 0,    Wg, 768, 0,
        gbuf, 1536, 0);

    // ---- output gate pre-activation ----
    gemm64<<<dim3(64, 4, 1), 256, 0, stream>>>(0,
        Rbuf, 1536, 0, 1536, OWb, 1536, 0,
        Rbuf, 1536, 0, 0,    OWb, 1536, 0,
        opre, 512, 0);

    // ---- h_t, c_t ----
    cell_epilogue<<<8192, 256, 0, stream>>>(gbuf, opre, c_prev, f_b, i_b, g_b, o_b, out);
}